// Round 9
// baseline (2637.489 us; speedup 1.0000x reference)
//
#include <hip/hip_runtime.h>
#include <stdint.h>

typedef __attribute__((ext_vector_type(8))) short short8;
typedef __attribute__((ext_vector_type(4))) float f32x4;

#define NT 15

// packed bf16 weight fragments in d_ws (element offsets, shorts)
#define SET0 0          // L0: 32 (jt,g) pairs x 5 kt x 512
#define SET1 81920      // L1: 32 pairs x 8 kt x 512
#define SET2 212992     // dec: same shape as L1
#define SET3 344064     // heads (unused by main now, kept for layout stability)
#define PK_TOTAL 346112
#define DD_OFF (PK_TOTAL*2)   // byte offset of dec-const block in ws:
                              // dbase[1280] | hw[768] | hb[6] | hc[6]  (floats)

__device__ __forceinline__ unsigned short f2bf(float f){
  unsigned int u = __builtin_bit_cast(unsigned int, f);
  u += 0x7fffu + ((u >> 16) & 1u);
  return (unsigned short)(u >> 16);
}
__device__ __forceinline__ float sigf(float x){
  return __builtin_amdgcn_rcpf(1.0f + __expf(-x));
}
__device__ __forceinline__ float tanhf_(float x){
  return 1.0f - 2.0f*__builtin_amdgcn_rcpf(1.0f + __expf(2.0f*x));
}
// XOR-swizzled LDS index (shorts): spreads stride-256B rows across banks.
__device__ __forceinline__ int sidx(int row, int col){
  return row*128 + (col ^ ((row & 7) << 3));
}
// Raw workgroup barrier: LDS visibility only.
__device__ __forceinline__ void BAR(){
  asm volatile("s_waitcnt lgkmcnt(0)" ::: "memory");
  __builtin_amdgcn_s_barrier();
}

// ---------------- prep: pack weights to bf16 MFMA fragments ----------------
__global__ void pack_w(const float* __restrict__ Wih0, const float* __restrict__ Whh0,
                       const float* __restrict__ Wih1, const float* __restrict__ Whh1,
                       const float* __restrict__ Wihd, const float* __restrict__ Whhd,
                       const float* __restrict__ Wm,  const float* __restrict__ Ws,
                       unsigned short* __restrict__ pk)
{
  int idx = blockIdx.x*256 + threadIdx.x;
  if (idx >= PK_TOTAL) return;
  float v = 0.f;
  if (idx >= SET3){
    int e = idx - SET3;
    int j = e & 7, lane = (e >> 3) & 63, kt = e >> 9;
    int n = lane & 15;
    int k = kt*32 + (lane >> 4)*8 + j;
    if (n < 3) v = Wm[n*128 + k];
    else if (n < 6) v = Ws[(n-3)*128 + k];
  } else {
    int set, e;
    if (idx < SET1){ set = 0; e = idx; }
    else if (idx < SET2){ set = 1; e = idx - SET1; }
    else { set = 2; e = idx - SET2; }
    int j = e & 7, lane = (e >> 3) & 63, rest = e >> 9;
    int nf = (set == 0) ? 5 : 8;
    int kt = rest % nf, pair = rest / nf;
    int g = pair & 3, jt = pair >> 2;
    int n = g*128 + jt*16 + (lane & 15);
    int kk = (lane >> 4)*8 + j;
    if (set == 0){
      if (kt < 4) v = Whh0[n*128 + kt*32 + kk];          // K 0..127 = h0
      else if (kk < 6) v = Wih0[n*6 + kk];               // K-ext tile = x
    } else {
      const float* Wi = (set == 1) ? Wih1 : Wihd;
      const float* Wh = (set == 1) ? Whh1 : Whhd;
      v = (kt < 4) ? Wi[n*128 + kt*32 + kk] : Wh[n*128 + (kt-4)*32 + kk];
    }
  }
  pk[idx] = f2bf(v);
}

// decoder constants (see r7)
__global__ void prep_dec(const float* __restrict__ emb, const float* __restrict__ Wp,
                         const float* __restrict__ bp,
                         const float* __restrict__ Wm, const float* __restrict__ Ws,
                         const float* __restrict__ bm, const float* __restrict__ bs,
                         const float* __restrict__ lng, const float* __restrict__ lnb,
                         float* __restrict__ dd)
{
  int idx = blockIdx.x*128 + threadIdx.x;
  if (idx < 1280){
    int s = idx >> 7, j = idx & 127;
    float acc = bp[j];
    for (int k = 0; k < 128; ++k) acc += emb[s*128 + k] * Wp[j*131 + 3 + k];
    dd[idx] = acc;
  } else if (idx < 2048){
    int e = idx - 1280; int o = e >> 7, j = e & 127;
    const float* W = (o < 3) ? (Wm + o*128) : (Ws + (o-3)*128);
    dd[idx] = W[j] * lng[j];
  } else if (idx < 2054){
    int o = idx - 2048;
    const float* W = (o < 3) ? (Wm + o*128) : (Ws + (o-3)*128);
    float a = 0.f;
    for (int k = 0; k < 128; ++k) a += W[k]*lng[k];
    dd[idx] = a;
  } else if (idx < 2060){
    int o = idx - 2054;
    const float* W = (o < 3) ? (Wm + o*128) : (Ws + (o-3)*128);
    float a = (o < 3) ? bm[o] : bs[o-3];
    for (int k = 0; k < 128; ++k) a += W[k]*lnb[k];
    dd[idx] = a;
  }
}

// ---------------- main fused kernel ----------------
// r9: m-SPLIT every MFMA phase (rows in two halves) -> acc[2][4] (32 regs)
// instead of acc[4][4] (64). True live set ~120-130 <= the compiler's chosen
// 128 cap -> NO scratch spills. r1-r8 evidence: WRITE_SIZE 290-500MB (vs
// 16MB compulsory) = per-thread scratch; its L2 churn caused 21% weight-fetch
// misses to HBM, which was the phase-latency clock. Weights stream twice per
// phase now (L2-hot, ~17GB chip-wide ~0.5ms of L2 BW - not binding).
__global__ __launch_bounds__(512, 2)
void traj_main(const float* __restrict__ x,
               const unsigned short* __restrict__ pk,
               const float* __restrict__ dd,
               const float* __restrict__ b0g, const float* __restrict__ b1g,
               const float* __restrict__ bdg,
               const float* __restrict__ Wp,
               float* __restrict__ out)
{
  __shared__ __align__(16) unsigned short hP[3][64*128];
  __shared__ __align__(16) union {
    unsigned short xs[NT*64*8];                        // 15360 B (encoder)
    struct { float om[64][30]; float os[64][30]; } o;  // 15360 B (decoder)
  } u2;
  __shared__ __align__(16) struct {
    float sred[8][64][8];    // per-wave partials: s1,s2,A0..A5
    float prevb[64][4];
  } u;

  const int tid  = threadIdx.x;
  const int w    = tid >> 6;
  const int lane = tid & 63;
  const int lidx = lane & 15;
  const int lgrp = lane >> 4;
  const int col  = w*16 + lidx;
  const int row0 = blockIdx.x * 64;

  for (int i = tid; i < 64*128; i += 512){ hP[0][i] = 0; hP[1][i] = 0; }
  for (int i = tid; i < NT*64*8; i += 512){
    int k8 = i & 7, rt = i >> 3;
    int r = rt & 63, t = rt >> 6;
    u2.xs[i] = (k8 < 6) ? f2bf(x[(size_t)(row0 + r)*90 + t*6 + k8])
                        : (unsigned short)0;
  }

  float b0v[4], b1v[4];
  #pragma unroll
  for (int g = 0; g < 4; ++g){ b0v[g] = b0g[g*128 + col]; b1v[g] = b1g[g*128 + col]; }

  float c0[4][4], c1[4][4];
  #pragma unroll
  for (int m = 0; m < 4; ++m)
    #pragma unroll
    for (int r = 0; r < 4; ++r){ c0[m][r] = 0.f; c1[m][r] = 0.f; }

  __syncthreads();

  const unsigned short* pw0 = pk + SET0 + (w*4)*(5*512) + lane*8;
  const unsigned short* pw1 = pk + SET1 + (w*4)*(8*512) + lane*8;
  const unsigned short* pw2 = pk + SET2 + (w*4)*(8*512) + lane*8;
  const short8 z8 = {0,0,0,0,0,0,0,0};

  int i0 = 0, i1 = 1, ifr = 2;
  #pragma unroll 1
  for (int t = 0; t < NT; ++t){
    const unsigned short* bh0 = &hP[i0][0];
    const unsigned short* bh1 = &hP[i1][0];
    unsigned short*       bnw = &hP[ifr][0];

    // ---------- layer 0: [h0 | x_t] @ W^T ; read bh0, write bnw ----------
    #pragma unroll 1
    for (int mh = 0; mh < 2; ++mh){
      f32x4 acc[2][4];
      #pragma unroll
      for (int mi = 0; mi < 2; ++mi)
        #pragma unroll
        for (int g = 0; g < 4; ++g)
          acc[mi][g] = (f32x4){b0v[g], b0v[g], b0v[g], b0v[g]};
      #pragma unroll
      for (int kt = 0; kt < 5; ++kt){
        short8 am[2];
        #pragma unroll
        for (int mi = 0; mi < 2; ++mi){
          const int arow = (mh*2 + mi)*16 + lidx;
          if (kt < 4)
            am[mi] = *(const short8*)&bh0[sidx(arow, kt*32 + lgrp*8)];
          else
            am[mi] = (lgrp == 0) ? *(const short8*)&u2.xs[(t*64 + arow)*8] : z8;
        }
        #pragma unroll
        for (int g = 0; g < 4; ++g){
          short8 wv = *(const short8*)&pw0[(g*5 + kt)*512];
          #pragma unroll
          for (int mi = 0; mi < 2; ++mi)
            acc[mi][g] = __builtin_amdgcn_mfma_f32_16x16x32_bf16(am[mi], wv, acc[mi][g], 0, 0, 0);
        }
      }
      #pragma unroll
      for (int mi = 0; mi < 2; ++mi){
        const int m = mh*2 + mi;
        #pragma unroll
        for (int r = 0; r < 4; ++r){
          float iv = sigf(acc[mi][0][r]);
          float fv = sigf(acc[mi][1][r]);
          float gv = tanhf_(acc[mi][2][r]);
          float ov = sigf(acc[mi][3][r]);
          float c = fv*c0[m][r] + iv*gv;
          c0[m][r] = c;
          bnw[sidx(m*16 + lgrp*4 + r, col)] = f2bf(ov*tanhf_(c));
        }
      }
    }
    BAR();   // bnw (new h0) visible; bh0 now dead

    // ---------- layer 1: [h0_new | h1] @ W^T ; read bnw,bh1, write bh0 ----------
    #pragma unroll 1
    for (int mh = 0; mh < 2; ++mh){
      f32x4 acc[2][4];
      #pragma unroll
      for (int mi = 0; mi < 2; ++mi)
        #pragma unroll
        for (int g = 0; g < 4; ++g)
          acc[mi][g] = (f32x4){b1v[g], b1v[g], b1v[g], b1v[g]};
      #pragma unroll
      for (int kt = 0; kt < 8; ++kt){
        short8 am[2];
        #pragma unroll
        for (int mi = 0; mi < 2; ++mi){
          const int arow = (mh*2 + mi)*16 + lidx;
          if (kt < 4)
            am[mi] = *(const short8*)&bnw[sidx(arow, kt*32 + lgrp*8)];
          else
            am[mi] = *(const short8*)&bh1[sidx(arow, (kt-4)*32 + lgrp*8)];
        }
        #pragma unroll
        for (int g = 0; g < 4; ++g){
          short8 wv = *(const short8*)&pw1[(g*8 + kt)*512];
          #pragma unroll
          for (int mi = 0; mi < 2; ++mi)
            acc[mi][g] = __builtin_amdgcn_mfma_f32_16x16x32_bf16(am[mi], wv, acc[mi][g], 0, 0, 0);
        }
      }
      unsigned short* bwr = const_cast<unsigned short*>(bh0);
      #pragma unroll
      for (int mi = 0; mi < 2; ++mi){
        const int m = mh*2 + mi;
        #pragma unroll
        for (int r = 0; r < 4; ++r){
          float iv = sigf(acc[mi][0][r]);
          float fv = sigf(acc[mi][1][r]);
          float gv = tanhf_(acc[mi][2][r]);
          float ov = sigf(acc[mi][3][r]);
          float c = fv*c1[m][r] + iv*gv;
          c1[m][r] = c;
          bwr[sidx(m*16 + lgrp*4 + r, col)] = f2bf(ov*tanhf_(c));
        }
      }
    }
    BAR();   // new h1 (in old-h0 slot) visible
    int t0 = i0; i0 = ifr; ifr = i1; i1 = t0;
  }
  // after 15 steps (period 3): h1 lives in hP[1].

  // ===================== decoder =====================
  const float* dbase = dd;
  const float* hwp   = dd + 1280;
  const float* hbp   = dd + 2048;
  const float* hcp   = dd + 2054;

  const float wpa = Wp[col*131 + 0], wpb = Wp[col*131 + 1], wpc = Wp[col*131 + 2];
  float bdv[4];
  #pragma unroll
  for (int g = 0; g < 4; ++g) bdv[g] = bdg[g*128 + col];
  float hwv[6], hbv[6], hcv[6];
  #pragma unroll
  for (int o = 0; o < 6; ++o){
    hwv[o] = hwp[o*128 + col];
    hbv[o] = hbp[o];
    hcv[o] = hcp[o];
  }

  if (tid < 192){
    int r = tid / 3, o = tid - r*3;
    u.prevb[r][o] = x[(size_t)(row0 + r)*90 + 14*6 + o];
  }
  __syncthreads();   // also separates u2 role switch xs -> obuf

  int hcur = 1, hnew = 0;          // h1 buffer / target; hP[2] = dec_in
  #pragma unroll 1
  for (int s = 0; s < 10; ++s){
    unsigned short* bdin = &hP[2][0];
    const unsigned short* bh = &hP[hcur][0];
    unsigned short* bhn = &hP[hnew][0];

    // ph1: dec_in = relu(dbase + prev @ Wp3^T) -> hP[2]
    const float dbs = dbase[s*128 + col];
    #pragma unroll
    for (int m = 0; m < 4; ++m)
      #pragma unroll
      for (int r = 0; r < 4; ++r){
        const int row = m*16 + lgrp*4 + r;
        f32x4 pv = *(const f32x4*)&u.prevb[row][0];
        float v = dbs + pv[0]*wpa + pv[1]*wpb + pv[2]*wpc;
        bdin[sidx(row, col)] = f2bf(v > 0.f ? v : 0.f);
      }
    BAR();

    // ph2: LSTM cell (kt-outer, m-split) + fused LN/head partials
    #pragma unroll 1
    for (int mh = 0; mh < 2; ++mh){
      f32x4 acc[2][4];
      #pragma unroll
      for (int mi = 0; mi < 2; ++mi)
        #pragma unroll
        for (int g = 0; g < 4; ++g)
          acc[mi][g] = (f32x4){bdv[g], bdv[g], bdv[g], bdv[g]};
      #pragma unroll
      for (int kt = 0; kt < 8; ++kt){
        short8 am[2];
        #pragma unroll
        for (int mi = 0; mi < 2; ++mi){
          const int arow = (mh*2 + mi)*16 + lidx;
          if (kt < 4)
            am[mi] = *(const short8*)&bdin[sidx(arow, kt*32 + lgrp*8)];
          else
            am[mi] = *(const short8*)&bh[sidx(arow, (kt-4)*32 + lgrp*8)];
        }
        #pragma unroll
        for (int g = 0; g < 4; ++g){
          short8 wv = *(const short8*)&pw2[(g*8 + kt)*512];
          #pragma unroll
          for (int mi = 0; mi < 2; ++mi)
            acc[mi][g] = __builtin_amdgcn_mfma_f32_16x16x32_bf16(am[mi], wv, acc[mi][g], 0, 0, 0);
        }
      }
      #pragma unroll
      for (int mi = 0; mi < 2; ++mi){
        const int m = mh*2 + mi;
        #pragma unroll
        for (int r = 0; r < 4; ++r){
          float iv = sigf(acc[mi][0][r]);
          float fv = sigf(acc[mi][1][r]);
          float gv = tanhf_(acc[mi][2][r]);
          float ov = sigf(acc[mi][3][r]);
          float c = fv*c1[m][r] + iv*gv;
          c1[m][r] = c;
          float h = ov*tanhf_(c);
          const int row = m*16 + lgrp*4 + r;
          bhn[sidx(row, col)] = f2bf(h);
          float vals[8];
          vals[0] = h; vals[1] = h*h;
          #pragma unroll
          for (int o = 0; o < 6; ++o) vals[2+o] = h*hwv[o];
          #pragma unroll
          for (int d = 1; d < 16; d <<= 1)
            #pragma unroll
            for (int k = 0; k < 8; ++k)
              vals[k] += __shfl_xor(vals[k], d);
          if (lidx == 0){
            *(f32x4*)&u.sred[w][row][0] = (f32x4){vals[0], vals[1], vals[2], vals[3]};
            *(f32x4*)&u.sred[w][row][4] = (f32x4){vals[4], vals[5], vals[6], vals[7]};
          }
        }
      }
    }
    BAR();

    // ph3: per-row finalize (stats + both heads), one thread per row
    if (tid < 64){
      float s1 = 0.f, s2 = 0.f;
      float A[6] = {0.f, 0.f, 0.f, 0.f, 0.f, 0.f};
      #pragma unroll
      for (int ww = 0; ww < 8; ++ww){
        f32x4 v0 = *(const f32x4*)&u.sred[ww][tid][0];
        f32x4 v1 = *(const f32x4*)&u.sred[ww][tid][4];
        s1 += v0[0]; s2 += v0[1];
        A[0] += v0[2]; A[1] += v0[3];
        A[2] += v1[0]; A[3] += v1[1]; A[4] += v1[2]; A[5] += v1[3];
      }
      float mu = s1 * (1.f/128.f);
      float var = s2 * (1.f/128.f) - mu*mu;
      float rs = __builtin_amdgcn_rsqf(var + 1e-5f);
      #pragma unroll
      for (int o = 0; o < 3; ++o){
        float v = rs*(A[o] - mu*hbv[o]) + hcv[o];
        u2.o.om[tid][s*3 + o] = v;
        u.prevb[tid][o] = v;
      }
      #pragma unroll
      for (int o = 3; o < 6; ++o){
        float v = rs*(A[o] - mu*hbv[o]) + hcv[o];
        u2.o.os[tid][s*3 + (o-3)] = fminf(fmaxf(v, -6.f), 3.f);
      }
    }
    BAR();
    int tswap = hcur; hcur = hnew; hnew = tswap;
  }

  // ---- single coalesced output flush ----
  for (int i = tid; i < 1920; i += 512){
    int r = i / 30, cx = i - r*30;
    out[(size_t)(row0 + r)*30 + cx] = u2.o.om[r][cx];
    out[(size_t)65536*30 + (size_t)(row0 + r)*30 + cx] = u2.o.os[r][cx];
  }
}

extern "C" void kernel_launch(void* const* d_in, const int* in_sizes, int n_in,
                              void* d_out, int out_size, void* d_ws, size_t ws_size,
                              hipStream_t stream)
{
  const float* x    = (const float*)d_in[0];
  const float* Wih0 = (const float*)d_in[1];
  const float* Whh0 = (const float*)d_in[2];
  const float* b0   = (const float*)d_in[3];
  const float* Wih1 = (const float*)d_in[4];
  const float* Whh1 = (const float*)d_in[5];
  const float* b1   = (const float*)d_in[6];
  const float* Wihd = (const float*)d_in[7];
  const float* Whhd = (const float*)d_in[8];
  const float* bd   = (const float*)d_in[9];
  const float* emb  = (const float*)d_in[10];
  const float* Wp   = (const float*)d_in[11];
  const float* bp   = (const float*)d_in[12];
  const float* Wm   = (const float*)d_in[13];
  const float* bm   = (const float*)d_in[14];
  const float* Ws   = (const float*)d_in[15];
  const float* bs   = (const float*)d_in[16];
  const float* lng  = (const float*)d_in[17];
  const float* lnb  = (const float*)d_in[18];

  unsigned short* pkw = (unsigned short*)d_ws;
  float* dd = (float*)((char*)d_ws + DD_OFF);

  pack_w<<<(PK_TOTAL + 255)/256, 256, 0, stream>>>(Wih0, Whh0, Wih1, Whh1,
                                                   Wihd, Whhd, Wm, Ws, pkw);
  prep_dec<<<17, 128, 0, stream>>>(emb, Wp, bp, Wm, Ws, bm, bs, lng, lnb, dd);
  traj_main<<<1024, 512, 0, stream>>>(x, pkw, dd, b0, b1, bd, Wp, (float*)d_out);
}

// Round 10
// 2299.212 us; speedup vs baseline: 1.1471x; 1.1471x over previous
//
#include <hip/hip_runtime.h>
#include <stdint.h>

typedef __attribute__((ext_vector_type(8))) short short8;
typedef __attribute__((ext_vector_type(4))) float f32x4;

#define NT 15

// packed bf16 weight fragments in d_ws (element offsets, shorts)
#define SET0 0          // L0: 32 (jt,g) pairs x 5 kt x 512
#define SET1 81920      // L1: 32 pairs x 8 kt x 512
#define SET2 212992     // dec: same shape as L1
#define SET3 344064     // heads (unused by main now, kept for layout stability)
#define PK_TOTAL 346112
#define DD_OFF (PK_TOTAL*2)   // byte offset of dec-const block in ws:
                              // dbase[1280] | hw[768] | hb[6] | hc[6]  (floats)

__device__ __forceinline__ unsigned short f2bf(float f){
  unsigned int u = __builtin_bit_cast(unsigned int, f);
  u += 0x7fffu + ((u >> 16) & 1u);
  return (unsigned short)(u >> 16);
}
__device__ __forceinline__ float sigf(float x){
  return __builtin_amdgcn_rcpf(1.0f + __expf(-x));
}
__device__ __forceinline__ float tanhf_(float x){
  return 1.0f - 2.0f*__builtin_amdgcn_rcpf(1.0f + __expf(2.0f*x));
}
// XOR-swizzled LDS index (shorts): spreads stride-256B rows across banks.
__device__ __forceinline__ int sidx(int row, int col){
  return row*128 + (col ^ ((row & 7) << 3));
}
// Raw workgroup barrier: LDS visibility only.
__device__ __forceinline__ void BAR(){
  asm volatile("s_waitcnt lgkmcnt(0)" ::: "memory");
  __builtin_amdgcn_s_barrier();
}

// ---------------- prep: pack weights to bf16 MFMA fragments ----------------
__global__ void pack_w(const float* __restrict__ Wih0, const float* __restrict__ Whh0,
                       const float* __restrict__ Wih1, const float* __restrict__ Whh1,
                       const float* __restrict__ Wihd, const float* __restrict__ Whhd,
                       const float* __restrict__ Wm,  const float* __restrict__ Ws,
                       unsigned short* __restrict__ pk)
{
  int idx = blockIdx.x*256 + threadIdx.x;
  if (idx >= PK_TOTAL) return;
  float v = 0.f;
  if (idx >= SET3){
    int e = idx - SET3;
    int j = e & 7, lane = (e >> 3) & 63, kt = e >> 9;
    int n = lane & 15;
    int k = kt*32 + (lane >> 4)*8 + j;
    if (n < 3) v = Wm[n*128 + k];
    else if (n < 6) v = Ws[(n-3)*128 + k];
  } else {
    int set, e;
    if (idx < SET1){ set = 0; e = idx; }
    else if (idx < SET2){ set = 1; e = idx - SET1; }
    else { set = 2; e = idx - SET2; }
    int j = e & 7, lane = (e >> 3) & 63, rest = e >> 9;
    int nf = (set == 0) ? 5 : 8;
    int kt = rest % nf, pair = rest / nf;
    int g = pair & 3, jt = pair >> 2;
    int n = g*128 + jt*16 + (lane & 15);
    int kk = (lane >> 4)*8 + j;
    if (set == 0){
      if (kt < 4) v = Whh0[n*128 + kt*32 + kk];          // K 0..127 = h0
      else if (kk < 6) v = Wih0[n*6 + kk];               // K-ext tile = x
    } else {
      const float* Wi = (set == 1) ? Wih1 : Wihd;
      const float* Wh = (set == 1) ? Whh1 : Whhd;
      v = (kt < 4) ? Wi[n*128 + kt*32 + kk] : Wh[n*128 + (kt-4)*32 + kk];
    }
  }
  pk[idx] = f2bf(v);
}

// decoder constants (see r7)
__global__ void prep_dec(const float* __restrict__ emb, const float* __restrict__ Wp,
                         const float* __restrict__ bp,
                         const float* __restrict__ Wm, const float* __restrict__ Ws,
                         const float* __restrict__ bm, const float* __restrict__ bs,
                         const float* __restrict__ lng, const float* __restrict__ lnb,
                         float* __restrict__ dd)
{
  int idx = blockIdx.x*128 + threadIdx.x;
  if (idx < 1280){
    int s = idx >> 7, j = idx & 127;
    float acc = bp[j];
    for (int k = 0; k < 128; ++k) acc += emb[s*128 + k] * Wp[j*131 + 3 + k];
    dd[idx] = acc;
  } else if (idx < 2048){
    int e = idx - 1280; int o = e >> 7, j = e & 127;
    const float* W = (o < 3) ? (Wm + o*128) : (Ws + (o-3)*128);
    dd[idx] = W[j] * lng[j];
  } else if (idx < 2054){
    int o = idx - 2048;
    const float* W = (o < 3) ? (Wm + o*128) : (Ws + (o-3)*128);
    float a = 0.f;
    for (int k = 0; k < 128; ++k) a += W[k]*lng[k];
    dd[idx] = a;
  } else if (idx < 2060){
    int o = idx - 2054;
    const float* W = (o < 3) ? (Wm + o*128) : (Ws + (o-3)*128);
    float a = (o < 3) ? bm[o] : bs[o-3];
    for (int k = 0; k < 128; ++k) a += W[k]*lnb[k];
    dd[idx] = a;
  }
}

// ---------------- main fused kernel ----------------
// r10: REGISTER-PERSISTENT weights for L0 (20 frags = 80 VGPR, live only
// during encoder) and decoder (32 frags = 128 VGPR, loaded after encoder,
// decoder uses statically-unrolled m-split so live set ~229 <= 256 cap).
// Only L1 weights stream (15 of 55 phases). All array indices compile-time
// (r9's regression was #pragma unroll 1 making c[m] runtime-indexed ->
// scratch, rule #20).
__global__ __launch_bounds__(512, 2)
void traj_main(const float* __restrict__ x,
               const unsigned short* __restrict__ pk,
               const float* __restrict__ dd,
               const float* __restrict__ b0g, const float* __restrict__ b1g,
               const float* __restrict__ bdg,
               const float* __restrict__ Wp,
               float* __restrict__ out)
{
  __shared__ __align__(16) unsigned short hP[3][64*128];
  __shared__ __align__(16) union {
    unsigned short xs[NT*64*8];                        // 15360 B (encoder)
    struct { float om[64][30]; float os[64][30]; } o;  // 15360 B (decoder)
  } u2;
  __shared__ __align__(16) struct {
    float sred[8][64][8];    // per-wave partials: s1,s2,A0..A5
    float prevb[64][4];
  } u;

  const int tid  = threadIdx.x;
  const int w    = tid >> 6;
  const int lane = tid & 63;
  const int lidx = lane & 15;
  const int lgrp = lane >> 4;
  const int col  = w*16 + lidx;
  const int row0 = blockIdx.x * 64;

  for (int i = tid; i < 64*128; i += 512){ hP[0][i] = 0; hP[1][i] = 0; }
  for (int i = tid; i < NT*64*8; i += 512){
    int k8 = i & 7, rt = i >> 3;
    int r = rt & 63, t = rt >> 6;
    u2.xs[i] = (k8 < 6) ? f2bf(x[(size_t)(row0 + r)*90 + t*6 + k8])
                        : (unsigned short)0;
  }

  float b0v[4], b1v[4];
  #pragma unroll
  for (int g = 0; g < 4; ++g){ b0v[g] = b0g[g*128 + col]; b1v[g] = b1g[g*128 + col]; }

  float c0[4][4], c1[4][4];
  #pragma unroll
  for (int m = 0; m < 4; ++m)
    #pragma unroll
    for (int r = 0; r < 4; ++r){ c0[m][r] = 0.f; c1[m][r] = 0.f; }

  __syncthreads();

  const unsigned short* pw0 = pk + SET0 + (w*4)*(5*512) + lane*8;
  const unsigned short* pw1 = pk + SET1 + (w*4)*(8*512) + lane*8;
  const unsigned short* pw2 = pk + SET2 + (w*4)*(8*512) + lane*8;
  const short8 z8 = {0,0,0,0,0,0,0,0};

  // ---- L0 weights: PERSISTENT in registers (80 VGPR), encoder lifetime ----
  short8 w0p[20];
  #pragma unroll
  for (int g = 0; g < 4; ++g)
    #pragma unroll
    for (int kt = 0; kt < 5; ++kt)
      w0p[g*5 + kt] = *(const short8*)&pw0[(g*5 + kt)*512];

  int i0 = 0, i1 = 1, ifr = 2;
  #pragma unroll 1
  for (int t = 0; t < NT; ++t){
    const unsigned short* bh0 = &hP[i0][0];
    const unsigned short* bh1 = &hP[i1][0];
    unsigned short*       bnw = &hP[ifr][0];

    // ---------- layer 0 (no global loads: weights in regs) ----------
    {
      f32x4 acc[4][4];
      #pragma unroll
      for (int m = 0; m < 4; ++m)
        #pragma unroll
        for (int g = 0; g < 4; ++g)
          acc[m][g] = (f32x4){b0v[g], b0v[g], b0v[g], b0v[g]};
      #pragma unroll
      for (int kt = 0; kt < 5; ++kt){
        short8 am[4];
        #pragma unroll
        for (int m = 0; m < 4; ++m){
          const int arow = m*16 + lidx;
          if (kt < 4)
            am[m] = *(const short8*)&bh0[sidx(arow, kt*32 + lgrp*8)];
          else
            am[m] = (lgrp == 0) ? *(const short8*)&u2.xs[(t*64 + arow)*8] : z8;
        }
        #pragma unroll
        for (int g = 0; g < 4; ++g)
          #pragma unroll
          for (int m = 0; m < 4; ++m)
            acc[m][g] = __builtin_amdgcn_mfma_f32_16x16x32_bf16(am[m], w0p[g*5 + kt], acc[m][g], 0, 0, 0);
      }
      #pragma unroll
      for (int m = 0; m < 4; ++m)
        #pragma unroll
        for (int r = 0; r < 4; ++r){
          float iv = sigf(acc[m][0][r]);
          float fv = sigf(acc[m][1][r]);
          float gv = tanhf_(acc[m][2][r]);
          float ov = sigf(acc[m][3][r]);
          float c = fv*c0[m][r] + iv*gv;
          c0[m][r] = c;
          bnw[sidx(m*16 + lgrp*4 + r, col)] = f2bf(ov*tanhf_(c));
        }
    }
    BAR();   // bnw (new h0) visible; bh0 now dead

    // ---------- layer 1 (streamed weights) ----------
    {
      f32x4 acc[4][4];
      #pragma unroll
      for (int m = 0; m < 4; ++m)
        #pragma unroll
        for (int g = 0; g < 4; ++g)
          acc[m][g] = (f32x4){b1v[g], b1v[g], b1v[g], b1v[g]};
      #pragma unroll
      for (int kt = 0; kt < 8; ++kt){
        short8 am[4];
        #pragma unroll
        for (int m = 0; m < 4; ++m){
          const int arow = m*16 + lidx;
          if (kt < 4)
            am[m] = *(const short8*)&bnw[sidx(arow, kt*32 + lgrp*8)];
          else
            am[m] = *(const short8*)&bh1[sidx(arow, (kt-4)*32 + lgrp*8)];
        }
        #pragma unroll
        for (int g = 0; g < 4; ++g){
          short8 wv = *(const short8*)&pw1[(g*8 + kt)*512];
          #pragma unroll
          for (int m = 0; m < 4; ++m)
            acc[m][g] = __builtin_amdgcn_mfma_f32_16x16x32_bf16(am[m], wv, acc[m][g], 0, 0, 0);
        }
      }
      unsigned short* bwr = const_cast<unsigned short*>(bh0);
      #pragma unroll
      for (int m = 0; m < 4; ++m)
        #pragma unroll
        for (int r = 0; r < 4; ++r){
          float iv = sigf(acc[m][0][r]);
          float fv = sigf(acc[m][1][r]);
          float gv = tanhf_(acc[m][2][r]);
          float ov = sigf(acc[m][3][r]);
          float c = fv*c1[m][r] + iv*gv;
          c1[m][r] = c;
          bwr[sidx(m*16 + lgrp*4 + r, col)] = f2bf(ov*tanhf_(c));
        }
    }
    BAR();   // new h1 (in old-h0 slot) visible
    int t0 = i0; i0 = ifr; ifr = i1; i1 = t0;
  }
  // after 15 steps (period 3): h1 lives in hP[1].

  // ===================== decoder =====================
  const float* dbase = dd;
  const float* hwp   = dd + 1280;
  const float* hbp   = dd + 2048;
  const float* hcp   = dd + 2054;

  // ---- decoder weights: PERSISTENT in registers (128 VGPR); w0p is dead ----
  short8 wdf[32];
  #pragma unroll
  for (int g = 0; g < 4; ++g)
    #pragma unroll
    for (int kt = 0; kt < 8; ++kt)
      wdf[g*8 + kt] = *(const short8*)&pw2[(g*8 + kt)*512];

  const float wpa = Wp[col*131 + 0], wpb = Wp[col*131 + 1], wpc = Wp[col*131 + 2];
  float bdv[4];
  #pragma unroll
  for (int g = 0; g < 4; ++g) bdv[g] = bdg[g*128 + col];
  float hwv[6], hbv[6], hcv[6];
  #pragma unroll
  for (int o = 0; o < 6; ++o){
    hwv[o] = hwp[o*128 + col];
    hbv[o] = hbp[o];
    hcv[o] = hcp[o];
  }

  if (tid < 192){
    int r = tid / 3, o = tid - r*3;
    u.prevb[r][o] = x[(size_t)(row0 + r)*90 + 14*6 + o];
  }
  __syncthreads();   // also separates u2 role switch xs -> obuf

  int hcur = 1, hnew = 0;          // h1 buffer / target; hP[2] = dec_in
  #pragma unroll 1
  for (int s = 0; s < 10; ++s){
    unsigned short* bdin = &hP[2][0];
    const unsigned short* bh = &hP[hcur][0];
    unsigned short* bhn = &hP[hnew][0];

    // ph1: dec_in = relu(dbase + prev @ Wp3^T) -> hP[2]
    const float dbs = dbase[s*128 + col];
    #pragma unroll
    for (int m = 0; m < 4; ++m)
      #pragma unroll
      for (int r = 0; r < 4; ++r){
        const int row = m*16 + lgrp*4 + r;
        f32x4 pv = *(const f32x4*)&u.prevb[row][0];
        float v = dbs + pv[0]*wpa + pv[1]*wpb + pv[2]*wpc;
        bdin[sidx(row, col)] = f2bf(v > 0.f ? v : 0.f);
      }
    BAR();

    // ph2: LSTM cell, statically m-split (FULL unroll -> all indices
    // compile-time; acc scoped per half = 32 regs live, no loads at all)
    #pragma unroll
    for (int mh = 0; mh < 2; ++mh){
      f32x4 acc[2][4];
      #pragma unroll
      for (int mi = 0; mi < 2; ++mi)
        #pragma unroll
        for (int g = 0; g < 4; ++g)
          acc[mi][g] = (f32x4){bdv[g], bdv[g], bdv[g], bdv[g]};
      #pragma unroll
      for (int kt = 0; kt < 8; ++kt){
        short8 am[2];
        #pragma unroll
        for (int mi = 0; mi < 2; ++mi){
          const int arow = (mh*2 + mi)*16 + lidx;
          if (kt < 4)
            am[mi] = *(const short8*)&bdin[sidx(arow, kt*32 + lgrp*8)];
          else
            am[mi] = *(const short8*)&bh[sidx(arow, (kt-4)*32 + lgrp*8)];
        }
        #pragma unroll
        for (int g = 0; g < 4; ++g)
          #pragma unroll
          for (int mi = 0; mi < 2; ++mi)
            acc[mi][g] = __builtin_amdgcn_mfma_f32_16x16x32_bf16(am[mi], wdf[g*8 + kt], acc[mi][g], 0, 0, 0);
      }
      #pragma unroll
      for (int mi = 0; mi < 2; ++mi){
        const int m = mh*2 + mi;          // compile-time (both loops unrolled)
        #pragma unroll
        for (int r = 0; r < 4; ++r){
          float iv = sigf(acc[mi][0][r]);
          float fv = sigf(acc[mi][1][r]);
          float gv = tanhf_(acc[mi][2][r]);
          float ov = sigf(acc[mi][3][r]);
          float c = fv*c1[m][r] + iv*gv;
          c1[m][r] = c;
          float h = ov*tanhf_(c);
          const int row = m*16 + lgrp*4 + r;
          bhn[sidx(row, col)] = f2bf(h);
          float vals[8];
          vals[0] = h; vals[1] = h*h;
          #pragma unroll
          for (int o = 0; o < 6; ++o) vals[2+o] = h*hwv[o];
          #pragma unroll
          for (int d = 1; d < 16; d <<= 1)
            #pragma unroll
            for (int k = 0; k < 8; ++k)
              vals[k] += __shfl_xor(vals[k], d);
          if (lidx == 0){
            *(f32x4*)&u.sred[w][row][0] = (f32x4){vals[0], vals[1], vals[2], vals[3]};
            *(f32x4*)&u.sred[w][row][4] = (f32x4){vals[4], vals[5], vals[6], vals[7]};
          }
        }
      }
    }
    BAR();

    // ph3: per-row finalize (stats + both heads), one thread per row
    if (tid < 64){
      float s1 = 0.f, s2 = 0.f;
      float A[6] = {0.f, 0.f, 0.f, 0.f, 0.f, 0.f};
      #pragma unroll
      for (int ww = 0; ww < 8; ++ww){
        f32x4 v0 = *(const f32x4*)&u.sred[ww][tid][0];
        f32x4 v1 = *(const f32x4*)&u.sred[ww][tid][4];
        s1 += v0[0]; s2 += v0[1];
        A[0] += v0[2]; A[1] += v0[3];
        A[2] += v1[0]; A[3] += v1[1]; A[4] += v1[2]; A[5] += v1[3];
      }
      float mu = s1 * (1.f/128.f);
      float var = s2 * (1.f/128.f) - mu*mu;
      float rs = __builtin_amdgcn_rsqf(var + 1e-5f);
      #pragma unroll
      for (int o = 0; o < 3; ++o){
        float v = rs*(A[o] - mu*hbv[o]) + hcv[o];
        u2.o.om[tid][s*3 + o] = v;
        u.prevb[tid][o] = v;
      }
      #pragma unroll
      for (int o = 3; o < 6; ++o){
        float v = rs*(A[o] - mu*hbv[o]) + hcv[o];
        u2.o.os[tid][s*3 + (o-3)] = fminf(fmaxf(v, -6.f), 3.f);
      }
    }
    BAR();
    int tswap = hcur; hcur = hnew; hnew = tswap;
  }

  // ---- single coalesced output flush ----
  for (int i = tid; i < 1920; i += 512){
    int r = i / 30, cx = i - r*30;
    out[(size_t)(row0 + r)*30 + cx] = u2.o.om[r][cx];
    out[(size_t)65536*30 + (size_t)(row0 + r)*30 + cx] = u2.o.os[r][cx];
  }
}

extern "C" void kernel_launch(void* const* d_in, const int* in_sizes, int n_in,
                              void* d_out, int out_size, void* d_ws, size_t ws_size,
                              hipStream_t stream)
{
  const float* x    = (const float*)d_in[0];
  const float* Wih0 = (const float*)d_in[1];
  const float* Whh0 = (const float*)d_in[2];
  const float* b0   = (const float*)d_in[3];
  const float* Wih1 = (const float*)d_in[4];
  const float* Whh1 = (const float*)d_in[5];
  const float* b1   = (const float*)d_in[6];
  const float* Wihd = (const float*)d_in[7];
  const float* Whhd = (const float*)d_in[8];
  const float* bd   = (const float*)d_in[9];
  const float* emb  = (const float*)d_in[10];
  const float* Wp   = (const float*)d_in[11];
  const float* bp   = (const float*)d_in[12];
  const float* Wm   = (const float*)d_in[13];
  const float* bm   = (const float*)d_in[14];
  const float* Ws   = (const float*)d_in[15];
  const float* bs   = (const float*)d_in[16];
  const float* lng  = (const float*)d_in[17];
  const float* lnb  = (const float*)d_in[18];

  unsigned short* pkw = (unsigned short*)d_ws;
  float* dd = (float*)((char*)d_ws + DD_OFF);

  pack_w<<<(PK_TOTAL + 255)/256, 256, 0, stream>>>(Wih0, Whh0, Wih1, Whh1,
                                                   Wihd, Whhd, Wm, Ws, pkw);
  prep_dec<<<17, 128, 0, stream>>>(emb, Wp, bp, Wm, Ws, bm, bs, lng, lnb, dd);
  traj_main<<<1024, 512, 0, stream>>>(x, pkw, dd, b0, b1, bd, Wp, (float*)d_out);
}

// Round 11
// 2037.843 us; speedup vs baseline: 1.2943x; 1.1283x over previous
//
#include <hip/hip_runtime.h>
#include <stdint.h>

typedef __attribute__((ext_vector_type(8))) short short8;
typedef __attribute__((ext_vector_type(4))) float f32x4;

#define NT 15

// packed bf16 weight fragments in d_ws (element offsets, shorts)
#define SET0 0          // L0: 32 (jt,g) pairs x 5 kt x 512
#define SET1 81920      // L1: 32 pairs x 8 kt x 512
#define SET2 212992     // dec: same shape as L1
#define SET3 344064     // heads (unused by main now, kept for layout stability)
#define PK_TOTAL 346112
#define DD_OFF (PK_TOTAL*2)   // byte offset of dec-const block in ws:
                              // dbase[1280] | hw[768] | hb[6] | hc[6]  (floats)

__device__ __forceinline__ unsigned short f2bf(float f){
  unsigned int u = __builtin_bit_cast(unsigned int, f);
  u += 0x7fffu + ((u >> 16) & 1u);
  return (unsigned short)(u >> 16);
}
__device__ __forceinline__ float sigf(float x){
  return __builtin_amdgcn_rcpf(1.0f + __expf(-x));
}
__device__ __forceinline__ float tanhf_(float x){
  return 1.0f - 2.0f*__builtin_amdgcn_rcpf(1.0f + __expf(2.0f*x));
}
// XOR-swizzled LDS index (shorts): spreads stride-256B rows across banks.
__device__ __forceinline__ int sidx(int row, int col){
  return row*128 + (col ^ ((row & 7) << 3));
}
// Raw workgroup barrier: LDS visibility only.
__device__ __forceinline__ void BAR(){
  asm volatile("s_waitcnt lgkmcnt(0)" ::: "memory");
  __builtin_amdgcn_s_barrier();
}

// ---------------- prep: pack weights to bf16 MFMA fragments ----------------
__global__ void pack_w(const float* __restrict__ Wih0, const float* __restrict__ Whh0,
                       const float* __restrict__ Wih1, const float* __restrict__ Whh1,
                       const float* __restrict__ Wihd, const float* __restrict__ Whhd,
                       const float* __restrict__ Wm,  const float* __restrict__ Ws,
                       unsigned short* __restrict__ pk)
{
  int idx = blockIdx.x*256 + threadIdx.x;
  if (idx >= PK_TOTAL) return;
  float v = 0.f;
  if (idx >= SET3){
    int e = idx - SET3;
    int j = e & 7, lane = (e >> 3) & 63, kt = e >> 9;
    int n = lane & 15;
    int k = kt*32 + (lane >> 4)*8 + j;
    if (n < 3) v = Wm[n*128 + k];
    else if (n < 6) v = Ws[(n-3)*128 + k];
  } else {
    int set, e;
    if (idx < SET1){ set = 0; e = idx; }
    else if (idx < SET2){ set = 1; e = idx - SET1; }
    else { set = 2; e = idx - SET2; }
    int j = e & 7, lane = (e >> 3) & 63, rest = e >> 9;
    int nf = (set == 0) ? 5 : 8;
    int kt = rest % nf, pair = rest / nf;
    int g = pair & 3, jt = pair >> 2;
    int n = g*128 + jt*16 + (lane & 15);
    int kk = (lane >> 4)*8 + j;
    if (set == 0){
      if (kt < 4) v = Whh0[n*128 + kt*32 + kk];          // K 0..127 = h0
      else if (kk < 6) v = Wih0[n*6 + kk];               // K-ext tile = x
    } else {
      const float* Wi = (set == 1) ? Wih1 : Wihd;
      const float* Wh = (set == 1) ? Whh1 : Whhd;
      v = (kt < 4) ? Wi[n*128 + kt*32 + kk] : Wh[n*128 + (kt-4)*32 + kk];
    }
  }
  pk[idx] = f2bf(v);
}

// decoder constants (see r7)
__global__ void prep_dec(const float* __restrict__ emb, const float* __restrict__ Wp,
                         const float* __restrict__ bp,
                         const float* __restrict__ Wm, const float* __restrict__ Ws,
                         const float* __restrict__ bm, const float* __restrict__ bs,
                         const float* __restrict__ lng, const float* __restrict__ lnb,
                         float* __restrict__ dd)
{
  int idx = blockIdx.x*128 + threadIdx.x;
  if (idx < 1280){
    int s = idx >> 7, j = idx & 127;
    float acc = bp[j];
    for (int k = 0; k < 128; ++k) acc += emb[s*128 + k] * Wp[j*131 + 3 + k];
    dd[idx] = acc;
  } else if (idx < 2048){
    int e = idx - 1280; int o = e >> 7, j = e & 127;
    const float* W = (o < 3) ? (Wm + o*128) : (Ws + (o-3)*128);
    dd[idx] = W[j] * lng[j];
  } else if (idx < 2054){
    int o = idx - 2048;
    const float* W = (o < 3) ? (Wm + o*128) : (Ws + (o-3)*128);
    float a = 0.f;
    for (int k = 0; k < 128; ++k) a += W[k]*lng[k];
    dd[idx] = a;
  } else if (idx < 2060){
    int o = idx - 2054;
    const float* W = (o < 3) ? (Wm + o*128) : (Ws + (o-3)*128);
    float a = (o < 3) ? bm[o] : bs[o-3];
    for (int k = 0; k < 128; ++k) a += W[k]*lnb[k];
    dd[idx] = a;
  }
}

// ---------------- main fused kernel ----------------
// r11: SOFTWARE-PIPELINED encoder. Phase k computes L0(t=k) AND L1(t=k-1)
// in one barrier phase: L1 consumes h0[k-1] written last phase, so both
// sections read only stable buffers. h0/h1 are 2-buffer ping-pongs.
// Encoder barriers: 30 -> 16; per-phase independent work (208 MFMA, two
// weight streams) deep enough to hide load latency. Decoder = r7's proven
// 3-phase form.
__global__ __launch_bounds__(512, 2)
void traj_main(const float* __restrict__ x,
               const unsigned short* __restrict__ pk,
               const float* __restrict__ dd,
               const float* __restrict__ b0g, const float* __restrict__ b1g,
               const float* __restrict__ bdg,
               const float* __restrict__ Wp,
               float* __restrict__ out)
{
  __shared__ __align__(16) unsigned short hA[2][64*128];  // h0 ping-pong / dec: hA[0]=din
  __shared__ __align__(16) unsigned short hB[2][64*128];  // h1 ping-pong
  __shared__ __align__(16) union {
    unsigned short xs[NT*64*8];                        // 15360 B (encoder)
    struct { float om[64][30]; float os[64][30]; } o;  // 15360 B (decoder)
  } u2;
  __shared__ __align__(16) struct {
    float sred[8][64][8];    // per-wave partials: s1,s2,A0..A5
    float prevb[64][4];
  } u;

  const int tid  = threadIdx.x;
  const int w    = tid >> 6;
  const int lane = tid & 63;
  const int lidx = lane & 15;
  const int lgrp = lane >> 4;
  const int col  = w*16 + lidx;
  const int row0 = blockIdx.x * 64;

  // zero only the buffers read as "state -1": hA[1] (h0[-1]), hB[1] (h1[-1])
  for (int i = tid; i < 64*128; i += 512){ hA[1][i] = 0; hB[1][i] = 0; }
  for (int i = tid; i < NT*64*8; i += 512){
    int k8 = i & 7, rt = i >> 3;
    int r = rt & 63, t = rt >> 6;
    u2.xs[i] = (k8 < 6) ? f2bf(x[(size_t)(row0 + r)*90 + t*6 + k8])
                        : (unsigned short)0;
  }

  float b0v[4], b1v[4];
  #pragma unroll
  for (int g = 0; g < 4; ++g){ b0v[g] = b0g[g*128 + col]; b1v[g] = b1g[g*128 + col]; }

  float c0[4][4], c1[4][4];
  #pragma unroll
  for (int m = 0; m < 4; ++m)
    #pragma unroll
    for (int r = 0; r < 4; ++r){ c0[m][r] = 0.f; c1[m][r] = 0.f; }

  __syncthreads();

  const unsigned short* pw0 = pk + SET0 + (w*4)*(5*512) + lane*8;
  const unsigned short* pw1 = pk + SET1 + (w*4)*(8*512) + lane*8;
  const unsigned short* pw2 = pk + SET2 + (w*4)*(8*512) + lane*8;
  const short8 z8 = {0,0,0,0,0,0,0,0};

  // ======== pipelined encoder: phase k = L0(k) + L1(k-1), 16 phases ========
  #pragma unroll 1
  for (int k = 0; k <= NT; ++k){
    const unsigned short* h0rd = &hA[(k+1)&1][0];   // h0[k-1]
    unsigned short*       h0wr = &hA[k&1][0];       // h0[k]   (h0[k-2] dead)
    const unsigned short* h1rd = &hB[k&1][0];       // h1[k-2]
    unsigned short*       h1wr = &hB[(k+1)&1][0];   // h1[k-1] (h1[k-3] dead)

    if (k < NT){
      // ---- L0(t=k): [h0[k-1] | x_k] @ W0^T -> h0wr ----
      f32x4 acc[4][4];
      #pragma unroll
      for (int m = 0; m < 4; ++m)
        #pragma unroll
        for (int g = 0; g < 4; ++g)
          acc[m][g] = (f32x4){b0v[g], b0v[g], b0v[g], b0v[g]};
      #pragma unroll
      for (int kt = 0; kt < 5; ++kt){
        short8 am[4];
        #pragma unroll
        for (int m = 0; m < 4; ++m){
          const int arow = m*16 + lidx;
          if (kt < 4)
            am[m] = *(const short8*)&h0rd[sidx(arow, kt*32 + lgrp*8)];
          else
            am[m] = (lgrp == 0) ? *(const short8*)&u2.xs[(k*64 + arow)*8] : z8;
        }
        #pragma unroll
        for (int g = 0; g < 4; ++g){
          short8 wv = *(const short8*)&pw0[(g*5 + kt)*512];
          #pragma unroll
          for (int m = 0; m < 4; ++m)
            acc[m][g] = __builtin_amdgcn_mfma_f32_16x16x32_bf16(am[m], wv, acc[m][g], 0, 0, 0);
        }
      }
      #pragma unroll
      for (int m = 0; m < 4; ++m)
        #pragma unroll
        for (int r = 0; r < 4; ++r){
          float iv = sigf(acc[m][0][r]);
          float fv = sigf(acc[m][1][r]);
          float gv = tanhf_(acc[m][2][r]);
          float ov = sigf(acc[m][3][r]);
          float c = fv*c0[m][r] + iv*gv;
          c0[m][r] = c;
          h0wr[sidx(m*16 + lgrp*4 + r, col)] = f2bf(ov*tanhf_(c));
        }
    }

    if (k >= 1){
      // ---- L1(t=k-1): [h0[k-1] | h1[k-2]] @ W1^T -> h1wr ----
      f32x4 acc[4][4];
      #pragma unroll
      for (int m = 0; m < 4; ++m)
        #pragma unroll
        for (int g = 0; g < 4; ++g)
          acc[m][g] = (f32x4){b1v[g], b1v[g], b1v[g], b1v[g]};
      #pragma unroll
      for (int kt = 0; kt < 8; ++kt){
        short8 am[4];
        #pragma unroll
        for (int m = 0; m < 4; ++m){
          const int arow = m*16 + lidx;
          if (kt < 4)
            am[m] = *(const short8*)&h0rd[sidx(arow, kt*32 + lgrp*8)];
          else
            am[m] = *(const short8*)&h1rd[sidx(arow, (kt-4)*32 + lgrp*8)];
        }
        #pragma unroll
        for (int g = 0; g < 4; ++g){
          short8 wv = *(const short8*)&pw1[(g*8 + kt)*512];
          #pragma unroll
          for (int m = 0; m < 4; ++m)
            acc[m][g] = __builtin_amdgcn_mfma_f32_16x16x32_bf16(am[m], wv, acc[m][g], 0, 0, 0);
        }
      }
      #pragma unroll
      for (int m = 0; m < 4; ++m)
        #pragma unroll
        for (int r = 0; r < 4; ++r){
          float iv = sigf(acc[m][0][r]);
          float fv = sigf(acc[m][1][r]);
          float gv = tanhf_(acc[m][2][r]);
          float ov = sigf(acc[m][3][r]);
          float c = fv*c1[m][r] + iv*gv;
          c1[m][r] = c;
          h1wr[sidx(m*16 + lgrp*4 + r, col)] = f2bf(ov*tanhf_(c));
        }
    }
    BAR();
  }
  // h1[14] (final) lives in hB[0]; hA[0]/hA[1]/hB[1] are dead.

  // ===================== decoder (r7 structure) =====================
  const float* dbase = dd;
  const float* hwp   = dd + 1280;
  const float* hbp   = dd + 2048;
  const float* hcp   = dd + 2054;

  const float wpa = Wp[col*131 + 0], wpb = Wp[col*131 + 1], wpc = Wp[col*131 + 2];
  float bdv[4];
  #pragma unroll
  for (int g = 0; g < 4; ++g) bdv[g] = bdg[g*128 + col];
  float hwv[6], hbv[6], hcv[6];
  #pragma unroll
  for (int o = 0; o < 6; ++o){
    hwv[o] = hwp[o*128 + col];
    hbv[o] = hbp[o];
    hcv[o] = hcp[o];
  }

  if (tid < 192){
    int r = tid / 3, o = tid - r*3;
    u.prevb[r][o] = x[(size_t)(row0 + r)*90 + 14*6 + o];
  }
  __syncthreads();   // also separates u2 role switch xs -> obuf

  int hcur = 0, hnew = 1;          // h1 in hB[0]; hA[0] = dec_in
  #pragma unroll 1
  for (int s = 0; s < 10; ++s){
    unsigned short* bdin = &hA[0][0];
    const unsigned short* bh = &hB[hcur][0];
    unsigned short* bhn = &hB[hnew][0];

    // ph1: dec_in = relu(dbase + prev @ Wp3^T) -> hA[0]
    const float dbs = dbase[s*128 + col];
    #pragma unroll
    for (int m = 0; m < 4; ++m)
      #pragma unroll
      for (int r = 0; r < 4; ++r){
        const int row = m*16 + lgrp*4 + r;
        f32x4 pv = *(const f32x4*)&u.prevb[row][0];
        float v = dbs + pv[0]*wpa + pv[1]*wpb + pv[2]*wpc;
        bdin[sidx(row, col)] = f2bf(v > 0.f ? v : 0.f);
      }
    BAR();

    // ph2: LSTM cell (kt-outer) + fused LN/head partials
    {
      f32x4 acc[4][4];
      #pragma unroll
      for (int m = 0; m < 4; ++m)
        #pragma unroll
        for (int g = 0; g < 4; ++g)
          acc[m][g] = (f32x4){bdv[g], bdv[g], bdv[g], bdv[g]};
      #pragma unroll
      for (int kt = 0; kt < 8; ++kt){
        short8 am[4];
        #pragma unroll
        for (int m = 0; m < 4; ++m){
          const int arow = m*16 + lidx;
          if (kt < 4)
            am[m] = *(const short8*)&bdin[sidx(arow, kt*32 + lgrp*8)];
          else
            am[m] = *(const short8*)&bh[sidx(arow, (kt-4)*32 + lgrp*8)];
        }
        #pragma unroll
        for (int g = 0; g < 4; ++g){
          short8 wv = *(const short8*)&pw2[(g*8 + kt)*512];
          #pragma unroll
          for (int m = 0; m < 4; ++m)
            acc[m][g] = __builtin_amdgcn_mfma_f32_16x16x32_bf16(am[m], wv, acc[m][g], 0, 0, 0);
        }
      }
      #pragma unroll
      for (int m = 0; m < 4; ++m)
        #pragma unroll
        for (int r = 0; r < 4; ++r){
          float iv = sigf(acc[m][0][r]);
          float fv = sigf(acc[m][1][r]);
          float gv = tanhf_(acc[m][2][r]);
          float ov = sigf(acc[m][3][r]);
          float c = fv*c1[m][r] + iv*gv;
          c1[m][r] = c;
          float h = ov*tanhf_(c);
          const int row = m*16 + lgrp*4 + r;
          bhn[sidx(row, col)] = f2bf(h);
          float vals[8];
          vals[0] = h; vals[1] = h*h;
          #pragma unroll
          for (int o = 0; o < 6; ++o) vals[2+o] = h*hwv[o];
          #pragma unroll
          for (int d = 1; d < 16; d <<= 1)
            #pragma unroll
            for (int kk = 0; kk < 8; ++kk)
              vals[kk] += __shfl_xor(vals[kk], d);
          if (lidx == 0){
            *(f32x4*)&u.sred[w][row][0] = (f32x4){vals[0], vals[1], vals[2], vals[3]};
            *(f32x4*)&u.sred[w][row][4] = (f32x4){vals[4], vals[5], vals[6], vals[7]};
          }
        }
    }
    BAR();

    // ph3: per-row finalize (stats + both heads), one thread per row
    if (tid < 64){
      float s1 = 0.f, s2 = 0.f;
      float A[6] = {0.f, 0.f, 0.f, 0.f, 0.f, 0.f};
      #pragma unroll
      for (int ww = 0; ww < 8; ++ww){
        f32x4 v0 = *(const f32x4*)&u.sred[ww][tid][0];
        f32x4 v1 = *(const f32x4*)&u.sred[ww][tid][4];
        s1 += v0[0]; s2 += v0[1];
        A[0] += v0[2]; A[1] += v0[3];
        A[2] += v1[0]; A[3] += v1[1]; A[4] += v1[2]; A[5] += v1[3];
      }
      float mu = s1 * (1.f/128.f);
      float var = s2 * (1.f/128.f) - mu*mu;
      float rs = __builtin_amdgcn_rsqf(var + 1e-5f);
      #pragma unroll
      for (int o = 0; o < 3; ++o){
        float v = rs*(A[o] - mu*hbv[o]) + hcv[o];
        u2.o.om[tid][s*3 + o] = v;
        u.prevb[tid][o] = v;
      }
      #pragma unroll
      for (int o = 3; o < 6; ++o){
        float v = rs*(A[o] - mu*hbv[o]) + hcv[o];
        u2.o.os[tid][s*3 + (o-3)] = fminf(fmaxf(v, -6.f), 3.f);
      }
    }
    BAR();
    int tswap = hcur; hcur = hnew; hnew = tswap;
  }

  // ---- single coalesced output flush ----
  for (int i = tid; i < 1920; i += 512){
    int r = i / 30, cx = i - r*30;
    out[(size_t)(row0 + r)*30 + cx] = u2.o.om[r][cx];
    out[(size_t)65536*30 + (size_t)(row0 + r)*30 + cx] = u2.o.os[r][cx];
  }
}

extern "C" void kernel_launch(void* const* d_in, const int* in_sizes, int n_in,
                              void* d_out, int out_size, void* d_ws, size_t ws_size,
                              hipStream_t stream)
{
  const float* x    = (const float*)d_in[0];
  const float* Wih0 = (const float*)d_in[1];
  const float* Whh0 = (const float*)d_in[2];
  const float* b0   = (const float*)d_in[3];
  const float* Wih1 = (const float*)d_in[4];
  const float* Whh1 = (const float*)d_in[5];
  const float* b1   = (const float*)d_in[6];
  const float* Wihd = (const float*)d_in[7];
  const float* Whhd = (const float*)d_in[8];
  const float* bd   = (const float*)d_in[9];
  const float* emb  = (const float*)d_in[10];
  const float* Wp   = (const float*)d_in[11];
  const float* bp   = (const float*)d_in[12];
  const float* Wm   = (const float*)d_in[13];
  const float* bm   = (const float*)d_in[14];
  const float* Ws   = (const float*)d_in[15];
  const float* bs   = (const float*)d_in[16];
  const float* lng  = (const float*)d_in[17];
  const float* lnb  = (const float*)d_in[18];

  unsigned short* pkw = (unsigned short*)d_ws;
  float* dd = (float*)((char*)d_ws + DD_OFF);

  pack_w<<<(PK_TOTAL + 255)/256, 256, 0, stream>>>(Wih0, Whh0, Wih1, Whh1,
                                                   Wihd, Whhd, Wm, Ws, pkw);
  prep_dec<<<17, 128, 0, stream>>>(emb, Wp, bp, Wm, Ws, bm, bs, lng, lnb, dd);
  traj_main<<<1024, 512, 0, stream>>>(x, pkw, dd, b0, b1, bd, Wp, (float*)d_out);
}